// Round 4
// baseline (512.732 us; speedup 1.0000x reference)
//
#include <hip/hip_runtime.h>
#include <hip/hip_bf16.h>
#include <cstdint>
#include <cstddef>

#define D_MODEL 1024
#define N_EXP   8
#define HID     4096
#define T_TOK   4096          // B*S
#define NPAIR   (T_TOK * 2)   // top-2

// ---------------- workspace layout (bytes) ----------------
#define WS_COUNTS   0
#define WS_CURSOR   32
#define WS_OFFSETS  64
#define WS_TOKE     128                       // tok_e[T][2] int
#define WS_TOKG     32896                     // tok_g[T][2] float
#define WS_LTOK     65664                     // list_tok[NPAIR] int
#define WS_LGATE    98432                     // list_gate[NPAIR] float
#define WS_XB       131328                    // xb[T][1024] bf16        (8 MB)
#define WS_WB       (WS_XB + 8388608)         // Wt shared buf bf16      (64 MB)
#define WS_H        (WS_WB + 67108864)        // H[NPAIR][4096] bf16     (64 MB)

typedef __attribute__((ext_vector_type(8))) short bf16x8;
typedef __attribute__((ext_vector_type(4))) float f32x4;
typedef unsigned short u16;

__device__ __forceinline__ u16 f2bf(float f) {
    unsigned u = __float_as_uint(f);
    u += 0x7FFFu + ((u >> 16) & 1u);          // RNE
    return (u16)(u >> 16);
}

__device__ __forceinline__ void glds16(const void* g, void* l) {
    __builtin_amdgcn_global_load_lds(
        (const __attribute__((address_space(1))) void*)g,
        (__attribute__((address_space(3))) void*)l, 16, 0, 0);
}

// Swizzled-stage chunk map (validated r3: conflicts 0, bit-exact output).
// LDS tile: rows x 32 bf16, 2 rows per 128B line (8 x 16B chunks), chunk slot
// XOR-swizzled by (line&7). Read side uses matching XOR -> conflict-free.
__device__ __forceinline__ void chunk_map(int c, int& row, int& kc) {
    const int line = c >> 3, c8 = c & 7, u = c8 ^ (line & 7);
    row = line * 2 + (u >> 2);
    kc  = (u & 3) * 8;                        // ushort offset in 32-wide K window
}

// ---------------------------------------------------------------------------
// Router (validated) + fused x -> bf16 emission
// ---------------------------------------------------------------------------
__global__ __launch_bounds__(256) void k_router(
    const float* __restrict__ x, const float* __restrict__ noise,
    const float* __restrict__ Wr, const float* __restrict__ br,
    const float* __restrict__ Wn, const float* __restrict__ bn,
    int* __restrict__ counts, int* __restrict__ tok_e, float* __restrict__ tok_g,
    u16* __restrict__ xb)
{
    const int t   = blockIdx.x;
    const int tid = threadIdx.x;
    const int e   = tid & 7;
    const int g   = tid >> 3;
    const float* xr = x + (size_t)t * D_MODEL;

    // emit bf16 copy of x (coalesced float4 -> ushort4)
    {
        const float4 v4 = *(const float4*)(xr + tid * 4);
        ushort4 o;
        o.x = f2bf(v4.x); o.y = f2bf(v4.y); o.z = f2bf(v4.z); o.w = f2bf(v4.w);
        *(ushort4*)(xb + (size_t)t * D_MODEL + tid * 4) = o;
    }

    float ar = 0.f, an = 0.f;
    const int ibase = g * 32;
    #pragma unroll 8
    for (int j = 0; j < 32; ++j) {
        const int i = ibase + j;
        const float xv = xr[i];
        ar = fmaf(xv, Wr[i * 8 + e], ar);
        an = fmaf(xv, Wn[i * 8 + e], an);
    }

    __shared__ float sR[256], sN[256];
    sR[tid] = ar; sN[tid] = an;
    __syncthreads();
    for (int off = 128; off >= 8; off >>= 1) {
        if (tid < off) { sR[tid] += sR[tid + off]; sN[tid] += sN[tid + off]; }
        __syncthreads();
    }

    __shared__ float lg[8];
    if (tid < 8) {
        const float z  = sN[tid] + bn[tid];
        const float sp = fmaxf(z, 0.f) + log1pf(expf(-fabsf(z)));
        lg[tid] = sR[tid] + br[tid] + sp * noise[t * 8 + tid];
    }
    __syncthreads();

    if (tid == 0) {
        float v0 = -INFINITY, v1 = -INFINITY;
        int   i0 = 0,         i1 = 0;
        #pragma unroll
        for (int ee = 0; ee < 8; ++ee) {
            const float v = lg[ee];
            if (v > v0)      { v1 = v0; i1 = i0; v0 = v; i0 = ee; }
            else if (v > v1) { v1 = v;  i1 = ee; }
        }
        const float ew  = expf(v1 - v0);
        const float inv = 1.f / (1.f + ew);
        tok_e[t * 2 + 0] = i0;
        tok_e[t * 2 + 1] = i1;
        tok_g[t * 2 + 0] = inv;
        tok_g[t * 2 + 1] = ew * inv;
        atomicAdd(&counts[i0], 1);
        atomicAdd(&counts[i1], 1);
    }
}

__global__ void k_prefix(const int* __restrict__ counts, int* __restrict__ offsets)
{
    if (threadIdx.x == 0 && blockIdx.x == 0) {
        int acc = 0;
        #pragma unroll
        for (int e = 0; e < N_EXP; ++e) { offsets[e] = acc; acc += counts[e]; }
    }
}

__global__ __launch_bounds__(256) void k_scatter(
    const int* __restrict__ tok_e, const float* __restrict__ tok_g,
    const int* __restrict__ offsets, int* __restrict__ cursor,
    int* __restrict__ list_tok, float* __restrict__ list_gate)
{
    const int gid = blockIdx.x * 256 + threadIdx.x;
    if (gid >= NPAIR) return;
    const int e = tok_e[gid];
    const int p = atomicAdd(&cursor[e], 1);
    const int slot = offsets[e] + p;
    list_tok[slot]  = gid >> 1;
    list_gate[slot] = tok_g[gid];
}

// Per-expert transpose+convert: f32 [E][R][C] -> bf16 [E][C][R]
__global__ __launch_bounds__(256) void k_cvtT(
    const float* __restrict__ in, u16* __restrict__ outp, int R, int C)
{
    const size_t esz = (size_t)R * C;
    const float* ine = in + (size_t)blockIdx.z * esz;
    u16* oute = outp + (size_t)blockIdx.z * esz;
    const int c0 = blockIdx.x * 32, r0 = blockIdx.y * 32;

    __shared__ float s[32][36];
    const int tid = threadIdx.x;
    const int lr = tid >> 3, lc = (tid & 7) * 4;
    const float4 v = *(const float4*)(ine + (size_t)(r0 + lr) * C + c0 + lc);
    s[lr][lc + 0] = v.x; s[lr][lc + 1] = v.y; s[lr][lc + 2] = v.z; s[lr][lc + 3] = v.w;
    __syncthreads();
    const int oc = tid >> 3, orp = (tid & 7) * 4;
    ushort4 o;
    o.x = f2bf(s[orp + 0][oc]); o.y = f2bf(s[orp + 1][oc]);
    o.z = f2bf(s[orp + 2][oc]); o.w = f2bf(s[orp + 3][oc]);
    *(ushort4*)(oute + (size_t)(c0 + oc) * R + r0 + orp) = o;
}

// ---------------------------------------------------------------------------
// Grouped MFMA GEMM1: H = relu(Xg @ W1t^T + b1).
// Tile 256x256, BK=32, 512 threads (8 waves, 2m x 4n), triple-buffered
// glds16 staging, counted vmcnt, XCD-swizzled 1-D grid (2 n-tiles per XCD).
// ---------------------------------------------------------------------------
__global__ __launch_bounds__(512, 1) void k_ffn1(
    const u16* __restrict__ xb,     // [T][1024]
    const u16* __restrict__ W1t,    // [E][4096][1024]
    const float* __restrict__ b1,
    const int* __restrict__ counts, const int* __restrict__ offsets,
    const int* __restrict__ list_tok,
    u16* __restrict__ H)            // [NPAIR][4096]
{
    // grid = 8 e * 16 n * 32 m = 4096. wg=(r&7)*64 + r>>3 -> n_t = wg>>5.
    const int bid = blockIdx.x;
    const int e   = bid >> 9;
    const int r   = bid & 511;
    const int wg  = ((r & 7) << 6) + (r >> 3);
    const int n_t = wg >> 5;
    const int m_t = wg & 31;

    const int cnt = counts[e];
    const int m0  = m_t * 256;
    if (m0 >= cnt) return;
    const int base = offsets[e];
    const int n0   = n_t * 256;
    const u16* __restrict__ Be = W1t + (size_t)e * (HID * D_MODEL);

    __shared__ __align__(16) u16 SA[3 * 8192];  // 3 x (256 rows x 32) bf16 = 48 KB
    __shared__ __align__(16) u16 SB[3 * 8192];
    __shared__ int stok[256];

    const int tid = threadIdx.x;
    if (tid < 256) stok[tid] = list_tok[base + min(m0 + tid, cnt - 1)];
    __syncthreads();

    int ar0, ak0, ar1, ak1;
    chunk_map(tid, ar0, ak0);
    chunk_map(tid + 512, ar1, ak1);
    const u16* Asrc0 = xb + (size_t)stok[ar0] * D_MODEL + ak0;
    const u16* Asrc1 = xb + (size_t)stok[ar1] * D_MODEL + ak1;
    const u16* Bsrc0 = Be + (size_t)(n0 + ar0) * D_MODEL + ak0;
    const u16* Bsrc1 = Be + (size_t)(n0 + ar1) * D_MODEL + ak1;

    const int lane = tid & 63, lr = lane & 15, hk = lane >> 4;
    const int w = tid >> 6, wm = w >> 2, wn = w & 3;        // 2m x 4n waves
    const int colb  = ((((lr & 1) << 2) + hk) ^ (lr >> 1)) << 4;
    const int baseA = ((wm * 64 + (lr >> 1)) << 7) + colb;  // wave rows wm*128
    const int baseB = ((wn * 32 + (lr >> 1)) << 7) + colb;  // wave cols wn*64

    float bias[4];
    #pragma unroll
    for (int j = 0; j < 4; ++j) bias[j] = b1[(size_t)e * HID + n0 + wn * 64 + j * 16 + lr];

    f32x4 acc[8][4] = {};

    auto STAGE = [&](int s, int t) {
        const int kt = t * 32;
        char* Ab = (char*)SA + s * 16384;
        char* Bb = (char*)SB + s * 16384;
        glds16(Asrc0 + kt, Ab + tid * 16);
        glds16(Asrc1 + kt, Ab + (tid + 512) * 16);
        glds16(Bsrc0 + kt, Bb + tid * 16);
        glds16(Bsrc1 + kt, Bb + (tid + 512) * 16);
    };
    auto COMPUTE = [&](int s) {
        const char* Ab = (const char*)SA + s * 16384;
        const char* Bb = (const char*)SB + s * 16384;
        bf16x8 a[8], b[4];
        #pragma unroll
        for (int i = 0; i < 8; ++i) a[i] = *(const bf16x8*)(Ab + baseA + i * 1024);
        #pragma unroll
        for (int j = 0; j < 4; ++j) b[j] = *(const bf16x8*)(Bb + baseB + j * 1024);
        #pragma unroll
        for (int i = 0; i < 8; ++i)
            #pragma unroll
            for (int j = 0; j < 4; ++j)
                acc[i][j] = __builtin_amdgcn_mfma_f32_16x16x32_bf16(a[i], b[j], acc[i][j], 0, 0, 0);
    };

    const int NT = D_MODEL / 32;                // 32
    STAGE(0, 0);
    STAGE(1, 1);
    int sc = 0;
    for (int t = 0; t < NT; ++t) {
        if (t == NT - 1) { asm volatile("s_waitcnt vmcnt(0)" ::: "memory"); }
        else             { asm volatile("s_waitcnt vmcnt(4)" ::: "memory"); }
        __builtin_amdgcn_s_barrier();
        __builtin_amdgcn_sched_barrier(0);
        if (t + 2 < NT) { int ss = sc + 2; if (ss >= 3) ss -= 3; STAGE(ss, t + 2); }
        __builtin_amdgcn_sched_barrier(0);
        COMPUTE(sc);
        if (++sc == 3) sc = 0;
    }

    #pragma unroll
    for (int i = 0; i < 8; ++i) {
        #pragma unroll
        for (int g = 0; g < 4; ++g) {
            const int m = m0 + wm * 128 + i * 16 + hk * 4 + g;
            if (m < cnt) {
                u16* dst = H + (size_t)(base + m) * HID + n0 + wn * 64 + lr;
                #pragma unroll
                for (int j = 0; j < 4; ++j)
                    dst[j * 16] = f2bf(fmaxf(acc[i][j][g] + bias[j], 0.f));
            }
        }
    }
}

// ---------------------------------------------------------------------------
// Grouped MFMA GEMM2: out += gate*(H @ W2t^T + b2). K=4096 split into 2
// halves (f32 atomic accumulate). 128x128 tile, 4-buffer depth-3 prefetch,
// counted vmcnt(8)/(4)/(0). XCD owns one n-tile per expert.
// ---------------------------------------------------------------------------
__global__ __launch_bounds__(256, 2) void k_ffn2(
    const u16* __restrict__ Hb,     // [NPAIR][4096]
    const u16* __restrict__ W2t,    // [E][1024][4096]
    const float* __restrict__ b2,
    const int* __restrict__ counts, const int* __restrict__ offsets,
    const int* __restrict__ list_tok, const float* __restrict__ list_gate,
    float* __restrict__ out)
{
    // grid = 8 e * (8 n * 64 m * 2 kh) = 8192. n_t = bid%8 -> XCD-exclusive.
    const int bid = blockIdx.x;
    const int e   = bid >> 10;
    const int r   = bid & 1023;
    const int wg  = ((r & 7) << 7) + (r >> 3);
    const int n_t = wg >> 7;
    const int rem = wg & 127;
    const int m_t = rem >> 1;
    const int kh  = rem & 1;

    const int cnt = counts[e];
    const int m0  = m_t * 128;
    if (m0 >= cnt) return;
    const int base = offsets[e];
    const int n0   = n_t * 128;
    const u16* __restrict__ Be = W2t + (size_t)e * (D_MODEL * HID);

    __shared__ __align__(16) u16 SA[4 * 4096];  // 4 x (128 x 32) = 32 KB
    __shared__ __align__(16) u16 SB[4 * 4096];
    __shared__ int   s_tok[128];
    __shared__ float s_gate[128];

    const int tid = threadIdx.x;
    if (tid < 128) {
        const int sl = base + min(m0 + tid, cnt - 1);
        s_tok[tid]  = list_tok[sl];
        s_gate[tid] = list_gate[sl];
    }
    __syncthreads();

    int ar0, ak0, ar1, ak1;
    chunk_map(tid, ar0, ak0);
    chunk_map(tid + 256, ar1, ak1);
    const int k0 = kh * (HID / 2);              // 0 or 2048
    const u16* Asrc0 = Hb + (size_t)(base + min(m0 + ar0, cnt - 1)) * HID + k0 + ak0;
    const u16* Asrc1 = Hb + (size_t)(base + min(m0 + ar1, cnt - 1)) * HID + k0 + ak1;
    const u16* Bsrc0 = Be + (size_t)(n0 + ar0) * HID + k0 + ak0;
    const u16* Bsrc1 = Be + (size_t)(n0 + ar1) * HID + k0 + ak1;

    const int lane = tid & 63, lr = lane & 15, hk = lane >> 4;
    const int w = tid >> 6, wm = w >> 1, wn = w & 1;
    const int colb  = ((((lr & 1) << 2) + hk) ^ (lr >> 1)) << 4;
    const int baseA = ((wm * 32 + (lr >> 1)) << 7) + colb;
    const int baseB = ((wn * 32 + (lr >> 1)) << 7) + colb;

    float bias[4];
    #pragma unroll
    for (int j = 0; j < 4; ++j)
        bias[j] = (kh == 0) ? b2[(size_t)e * D_MODEL + n0 + wn * 64 + j * 16 + lr] : 0.f;

    f32x4 acc[4][4] = {};

    auto STAGE = [&](int s, int t) {
        const int kt = t * 32;
        char* Ab = (char*)SA + s * 8192;
        char* Bb = (char*)SB + s * 8192;
        glds16(Asrc0 + kt, Ab + tid * 16);
        glds16(Asrc1 + kt, Ab + (tid + 256) * 16);
        glds16(Bsrc0 + kt, Bb + tid * 16);
        glds16(Bsrc1 + kt, Bb + (tid + 256) * 16);
    };
    auto COMPUTE = [&](int s) {
        const char* Ab = (const char*)SA + s * 8192;
        const char* Bb = (const char*)SB + s * 8192;
        bf16x8 a[4], b[4];
        #pragma unroll
        for (int i = 0; i < 4; ++i) a[i] = *(const bf16x8*)(Ab + baseA + i * 1024);
        #pragma unroll
        for (int j = 0; j < 4; ++j) b[j] = *(const bf16x8*)(Bb + baseB + j * 1024);
        #pragma unroll
        for (int i = 0; i < 4; ++i)
            #pragma unroll
            for (int j = 0; j < 4; ++j)
                acc[i][j] = __builtin_amdgcn_mfma_f32_16x16x32_bf16(a[i], b[j], acc[i][j], 0, 0, 0);
    };

    const int NT = (HID / 2) / 32;              // 64
    STAGE(0, 0);
    STAGE(1, 1);
    STAGE(2, 2);
    int sc = 0;
    for (int t = 0; t < NT; ++t) {
        if (t + 2 < NT)      { asm volatile("s_waitcnt vmcnt(8)" ::: "memory"); }
        else if (t + 1 < NT) { asm volatile("s_waitcnt vmcnt(4)" ::: "memory"); }
        else                 { asm volatile("s_waitcnt vmcnt(0)" ::: "memory"); }
        __builtin_amdgcn_s_barrier();
        __builtin_amdgcn_sched_barrier(0);
        if (t + 3 < NT) { STAGE((sc + 3) & 3, t + 3); }
        __builtin_amdgcn_sched_barrier(0);
        COMPUTE(sc);
        sc = (sc + 1) & 3;
    }

    #pragma unroll
    for (int i = 0; i < 4; ++i) {
        #pragma unroll
        for (int g = 0; g < 4; ++g) {
            const int m = m0 + wm * 64 + i * 16 + hk * 4 + g;
            if (m < cnt) {
                const int   mm = m - m0;
                const int   tk = s_tok[mm];
                const float gt = s_gate[mm];
                float* dst = out + (size_t)tk * D_MODEL + n0 + wn * 64 + lr;
                #pragma unroll
                for (int j = 0; j < 4; ++j)
                    unsafeAtomicAdd(dst + j * 16, gt * (acc[i][j][g] + bias[j]));
            }
        }
    }
}

// ---------------------------------------------------------------------------
extern "C" void kernel_launch(void* const* d_in, const int* in_sizes, int n_in,
                              void* d_out, int out_size, void* d_ws, size_t ws_size,
                              hipStream_t stream)
{
    const float* x     = (const float*)d_in[0];
    const float* noise = (const float*)d_in[1];
    const float* Wr    = (const float*)d_in[2];
    const float* br    = (const float*)d_in[3];
    const float* Wn    = (const float*)d_in[4];
    const float* bn    = (const float*)d_in[5];
    const float* W1    = (const float*)d_in[6];
    const float* b1    = (const float*)d_in[7];
    const float* W2    = (const float*)d_in[8];
    const float* b2    = (const float*)d_in[9];
    float* out = (float*)d_out;

    char* ws = (char*)d_ws;
    int*   counts    = (int*)(ws + WS_COUNTS);
    int*   cursor    = (int*)(ws + WS_CURSOR);
    int*   offsets   = (int*)(ws + WS_OFFSETS);
    int*   tok_e     = (int*)(ws + WS_TOKE);
    float* tok_g     = (float*)(ws + WS_TOKG);
    int*   list_tok  = (int*)(ws + WS_LTOK);
    float* list_gate = (float*)(ws + WS_LGATE);
    u16*   xb        = (u16*)(ws + WS_XB);
    u16*   Wb        = (u16*)(ws + WS_WB);
    u16*   Hb        = (u16*)(ws + WS_H);

    hipMemsetAsync(ws, 0, 128, stream);
    hipMemsetAsync(d_out, 0, (size_t)out_size * sizeof(float), stream);

    k_cvtT<<<dim3(HID / 32, D_MODEL / 32, N_EXP), 256, 0, stream>>>(W1, Wb, D_MODEL, HID);
    k_router<<<T_TOK, 256, 0, stream>>>(x, noise, Wr, br, Wn, bn, counts, tok_e, tok_g, xb);
    k_prefix<<<1, 64, 0, stream>>>(counts, offsets);
    k_scatter<<<NPAIR / 256, 256, 0, stream>>>(tok_e, tok_g, offsets, cursor,
                                               list_tok, list_gate);

    k_ffn1<<<N_EXP * 16 * 32, 512, 0, stream>>>(xb, Wb, b1, counts, offsets,
                                                list_tok, Hb);

    k_cvtT<<<dim3(D_MODEL / 32, HID / 32, N_EXP), 256, 0, stream>>>(W2, Wb, HID, D_MODEL);
    k_ffn2<<<N_EXP * 1024, 256, 0, stream>>>(Hb, Wb, b2, counts, offsets,
                                             list_tok, list_gate, out);
}

// Round 5
// 475.144 us; speedup vs baseline: 1.0791x; 1.0791x over previous
//
#include <hip/hip_runtime.h>
#include <hip/hip_bf16.h>
#include <cstdint>
#include <cstddef>

#define D_MODEL 1024
#define N_EXP   8
#define HID     4096
#define T_TOK   4096          // B*S
#define NPAIR   (T_TOK * 2)   // top-2

// ---------------- workspace layout (bytes) ----------------
#define WS_COUNTS   0
#define WS_CURSOR   32
#define WS_OFFSETS  64
#define WS_TOKE     128                       // tok_e[T][2] int
#define WS_TOKG     32896                     // tok_g[T][2] float
#define WS_LTOK     65664                     // list_tok[NPAIR] int
#define WS_LGATE    98432                     // list_gate[NPAIR] float
#define WS_XB       131328                    // xb[T][1024] bf16        (8 MB)
#define WS_WB       (WS_XB + 8388608)         // Wt shared buf bf16      (64 MB)
#define WS_H        (WS_WB + 67108864)        // H[NPAIR][4096] bf16     (64 MB)

typedef __attribute__((ext_vector_type(8)))  short bf16x8;
typedef __attribute__((ext_vector_type(16))) float f32x16;
typedef __attribute__((ext_vector_type(8)))  unsigned short u16x8;
typedef unsigned short u16;

__device__ __forceinline__ u16 f2bf(float f) {
    unsigned u = __float_as_uint(f);
    u += 0x7FFFu + ((u >> 16) & 1u);          // RNE
    return (u16)(u >> 16);
}

__device__ __forceinline__ void glds16(const void* g, void* l) {
    __builtin_amdgcn_global_load_lds(
        (const __attribute__((address_space(1))) void*)g,
        (__attribute__((address_space(3))) void*)l, 16, 0, 0);
}

// Swizzled-stage chunk map (validated r3: conflicts 0, bit-exact output).
// LDS tile: 128 rows x 32 bf16, 2 rows per 128B line (8 x 16B chunks), chunk
// slot XOR-swizzled by (line&7). Read side uses matching XOR.
__device__ __forceinline__ void chunk_map(int c, int& row, int& kc) {
    const int line = c >> 3, c8 = c & 7, u = c8 ^ (line & 7);
    row = line * 2 + (u >> 2);
    kc  = (u & 3) * 8;                        // ushort offset in 32-wide K window
}
// read-side byte offset for (row, 8-k chunk)
__device__ __forceinline__ int lds_off(int row, int chunk) {
    const int line = row >> 1;
    const int slot = (((row & 1) << 2) + chunk) ^ (line & 7);
    return line * 128 + slot * 16;
}

// ---------------------------------------------------------------------------
// Router (validated) + fused x -> bf16 emission (validated r4)
// ---------------------------------------------------------------------------
__global__ __launch_bounds__(256) void k_router(
    const float* __restrict__ x, const float* __restrict__ noise,
    const float* __restrict__ Wr, const float* __restrict__ br,
    const float* __restrict__ Wn, const float* __restrict__ bn,
    int* __restrict__ counts, int* __restrict__ tok_e, float* __restrict__ tok_g,
    u16* __restrict__ xb)
{
    const int t   = blockIdx.x;
    const int tid = threadIdx.x;
    const int e   = tid & 7;
    const int g   = tid >> 3;
    const float* xr = x + (size_t)t * D_MODEL;

    {
        const float4 v4 = *(const float4*)(xr + tid * 4);
        ushort4 o;
        o.x = f2bf(v4.x); o.y = f2bf(v4.y); o.z = f2bf(v4.z); o.w = f2bf(v4.w);
        *(ushort4*)(xb + (size_t)t * D_MODEL + tid * 4) = o;
    }

    float ar = 0.f, an = 0.f;
    const int ibase = g * 32;
    #pragma unroll 8
    for (int j = 0; j < 32; ++j) {
        const int i = ibase + j;
        const float xv = xr[i];
        ar = fmaf(xv, Wr[i * 8 + e], ar);
        an = fmaf(xv, Wn[i * 8 + e], an);
    }

    __shared__ float sR[256], sN[256];
    sR[tid] = ar; sN[tid] = an;
    __syncthreads();
    for (int off = 128; off >= 8; off >>= 1) {
        if (tid < off) { sR[tid] += sR[tid + off]; sN[tid] += sN[tid + off]; }
        __syncthreads();
    }

    __shared__ float lg[8];
    if (tid < 8) {
        const float z  = sN[tid] + bn[tid];
        const float sp = fmaxf(z, 0.f) + log1pf(expf(-fabsf(z)));
        lg[tid] = sR[tid] + br[tid] + sp * noise[t * 8 + tid];
    }
    __syncthreads();

    if (tid == 0) {
        float v0 = -INFINITY, v1 = -INFINITY;
        int   i0 = 0,         i1 = 0;
        #pragma unroll
        for (int ee = 0; ee < 8; ++ee) {
            const float v = lg[ee];
            if (v > v0)      { v1 = v0; i1 = i0; v0 = v; i0 = ee; }
            else if (v > v1) { v1 = v;  i1 = ee; }
        }
        const float ew  = expf(v1 - v0);
        const float inv = 1.f / (1.f + ew);
        tok_e[t * 2 + 0] = i0;
        tok_e[t * 2 + 1] = i1;
        tok_g[t * 2 + 0] = inv;
        tok_g[t * 2 + 1] = ew * inv;
        atomicAdd(&counts[i0], 1);
        atomicAdd(&counts[i1], 1);
    }
}

__global__ void k_prefix(const int* __restrict__ counts, int* __restrict__ offsets)
{
    if (threadIdx.x == 0 && blockIdx.x == 0) {
        int acc = 0;
        #pragma unroll
        for (int e = 0; e < N_EXP; ++e) { offsets[e] = acc; acc += counts[e]; }
    }
}

__global__ __launch_bounds__(256) void k_scatter(
    const int* __restrict__ tok_e, const float* __restrict__ tok_g,
    const int* __restrict__ offsets, int* __restrict__ cursor,
    int* __restrict__ list_tok, float* __restrict__ list_gate)
{
    const int gid = blockIdx.x * 256 + threadIdx.x;
    if (gid >= NPAIR) return;
    const int e = tok_e[gid];
    const int p = atomicAdd(&cursor[e], 1);
    const int slot = offsets[e] + p;
    list_tok[slot]  = gid >> 1;
    list_gate[slot] = tok_g[gid];
}

// ---------------------------------------------------------------------------
// Per-expert transpose+convert: f32 [E][R][C] -> bf16 [E][C][R]
// Tile 64R x 32C. Writes are ushort8 -> 8 lanes form one 128B run per column.
// LDS stride 33 u16: column reads are 2-way (free) bank pattern.
// ---------------------------------------------------------------------------
__global__ __launch_bounds__(256) void k_cvtT(
    const float* __restrict__ in, u16* __restrict__ outp, int R, int C)
{
    const size_t esz = (size_t)R * C;
    const float* ine = in + (size_t)blockIdx.z * esz;
    u16* oute = outp + (size_t)blockIdx.z * esz;
    const int c0 = blockIdx.x * 32, r0 = blockIdx.y * 64;

    __shared__ u16 s[64 * 33];
    const int tid = threadIdx.x;
    const int lr = tid >> 3, lc = (tid & 7) * 4;
    #pragma unroll
    for (int p = 0; p < 2; ++p) {
        const int row = lr + p * 32;
        const float4 v = *(const float4*)(ine + (size_t)(r0 + row) * C + c0 + lc);
        s[row * 33 + lc + 0] = f2bf(v.x);
        s[row * 33 + lc + 1] = f2bf(v.y);
        s[row * 33 + lc + 2] = f2bf(v.z);
        s[row * 33 + lc + 3] = f2bf(v.w);
    }
    __syncthreads();
    const int oc = tid >> 3, rr = (tid & 7) * 8;
    u16x8 o;
    #pragma unroll
    for (int i = 0; i < 8; ++i) o[i] = s[(rr + i) * 33 + oc];
    *(u16x8*)(oute + (size_t)(c0 + oc) * R + r0 + rr) = o;
}

// ---------------------------------------------------------------------------
// Grouped MFMA GEMM1: H = relu(Xg @ W1t^T + b1).
// r3-validated pipeline (128x128, BK=32, 3-buffer, vmcnt(4), XCD swizzle),
// inner math switched to v_mfma_f32_32x32x16_bf16: per wave 2x2 frags of
// 32x32, 2 k-substeps -> half the LDS reads and MFMA instrs of 16x16x32.
// ---------------------------------------------------------------------------
__global__ __launch_bounds__(256, 2) void k_ffn1(
    const u16* __restrict__ xb,     // [T][1024]
    const u16* __restrict__ W1t,    // [E][4096][1024]
    const float* __restrict__ b1,
    const int* __restrict__ counts, const int* __restrict__ offsets,
    const int* __restrict__ list_tok,
    u16* __restrict__ H)            // [NPAIR][4096]
{
    const int bid = blockIdx.x;
    const int e   = bid >> 11;
    const int r   = bid & 2047;
    const int wg  = ((r & 7) << 8) + (r >> 3);
    const int n_t = wg >> 6;
    const int m_t = wg & 63;

    const int cnt = counts[e];
    const int m0  = m_t * 128;
    if (m0 >= cnt) return;
    const int base = offsets[e];
    const int n0   = n_t * 128;
    const u16* __restrict__ Be = W1t + (size_t)e * (HID * D_MODEL);

    __shared__ __align__(16) u16 SA[3 * 4096];  // 3 x (128 x 32) bf16
    __shared__ __align__(16) u16 SB[3 * 4096];
    __shared__ int stok[128];

    const int tid = threadIdx.x;
    if (tid < 128) stok[tid] = list_tok[base + min(m0 + tid, cnt - 1)];
    __syncthreads();

    int ar0, ak0, ar1, ak1;
    chunk_map(tid, ar0, ak0);
    chunk_map(tid + 256, ar1, ak1);
    const u16* Asrc0 = xb + (size_t)stok[ar0] * D_MODEL + ak0;
    const u16* Asrc1 = xb + (size_t)stok[ar1] * D_MODEL + ak1;
    const u16* Bsrc0 = Be + (size_t)(n0 + ar0) * D_MODEL + ak0;
    const u16* Bsrc1 = Be + (size_t)(n0 + ar1) * D_MODEL + ak1;

    const int lane = tid & 63, l31 = lane & 31, l5 = lane >> 5;
    const int w = tid >> 6, wm = w >> 1, wn = w & 1;

    int offA[2][2], offB[2][2];           // [frag][k-substep]
    #pragma unroll
    for (int f = 0; f < 2; ++f)
        #pragma unroll
        for (int ks = 0; ks < 2; ++ks) {
            offA[f][ks] = lds_off(wm * 64 + f * 32 + l31, ks * 2 + l5);
            offB[f][ks] = lds_off(wn * 64 + f * 32 + l31, ks * 2 + l5);
        }

    float bias2[2];
    #pragma unroll
    for (int f = 0; f < 2; ++f)
        bias2[f] = b1[(size_t)e * HID + n0 + wn * 64 + f * 32 + l31];

    f32x16 acc[2][2] = {};

    auto STAGE = [&](int s, int t) {
        const int kt = t * 32;
        char* Ab = (char*)SA + s * 8192;
        char* Bb = (char*)SB + s * 8192;
        glds16(Asrc0 + kt, Ab + tid * 16);
        glds16(Asrc1 + kt, Ab + (tid + 256) * 16);
        glds16(Bsrc0 + kt, Bb + tid * 16);
        glds16(Bsrc1 + kt, Bb + (tid + 256) * 16);
    };
    auto COMPUTE = [&](int s) {
        const char* Ab = (const char*)SA + s * 8192;
        const char* Bb = (const char*)SB + s * 8192;
        #pragma unroll
        for (int ks = 0; ks < 2; ++ks) {
            const bf16x8 a0 = *(const bf16x8*)(Ab + offA[0][ks]);
            const bf16x8 a1 = *(const bf16x8*)(Ab + offA[1][ks]);
            const bf16x8 b0 = *(const bf16x8*)(Bb + offB[0][ks]);
            const bf16x8 b1v = *(const bf16x8*)(Bb + offB[1][ks]);
            acc[0][0] = __builtin_amdgcn_mfma_f32_32x32x16_bf16(a0, b0,  acc[0][0], 0, 0, 0);
            acc[0][1] = __builtin_amdgcn_mfma_f32_32x32x16_bf16(a0, b1v, acc[0][1], 0, 0, 0);
            acc[1][0] = __builtin_amdgcn_mfma_f32_32x32x16_bf16(a1, b0,  acc[1][0], 0, 0, 0);
            acc[1][1] = __builtin_amdgcn_mfma_f32_32x32x16_bf16(a1, b1v, acc[1][1], 0, 0, 0);
        }
    };

    const int NT = D_MODEL / 32;                // 32
    STAGE(0, 0);
    STAGE(1, 1);
    int sc = 0;
    for (int t = 0; t < NT; ++t) {
        if (t == NT - 1) { asm volatile("s_waitcnt vmcnt(0)" ::: "memory"); }
        else             { asm volatile("s_waitcnt vmcnt(4)" ::: "memory"); }
        __builtin_amdgcn_s_barrier();
        __builtin_amdgcn_sched_barrier(0);
        if (t + 2 < NT) { int ss = sc + 2; if (ss >= 3) ss -= 3; STAGE(ss, t + 2); }
        __builtin_amdgcn_sched_barrier(0);
        COMPUTE(sc);
        if (++sc == 3) sc = 0;
    }

    // C/D 32x32: col = lane&31, row = (reg&3) + 8*(reg>>2) + 4*(lane>>5)
    #pragma unroll
    for (int fi = 0; fi < 2; ++fi)
        #pragma unroll
        for (int fj = 0; fj < 2; ++fj)
            #pragma unroll
            for (int reg = 0; reg < 16; ++reg) {
                const int m = m0 + wm * 64 + fi * 32 + (reg & 3) + 8 * (reg >> 2) + 4 * l5;
                if (m < cnt) {
                    H[(size_t)(base + m) * HID + n0 + wn * 64 + fj * 32 + l31] =
                        f2bf(fmaxf(acc[fi][fj][reg] + bias2[fj], 0.f));
                }
            }
}

// ---------------------------------------------------------------------------
// Grouped MFMA GEMM2: out += gate*(H @ W2t^T + b2). K=4096. Same structure.
// ---------------------------------------------------------------------------
__global__ __launch_bounds__(256, 2) void k_ffn2(
    const u16* __restrict__ Hb,     // [NPAIR][4096]
    const u16* __restrict__ W2t,    // [E][1024][4096]
    const float* __restrict__ b2,
    const int* __restrict__ counts, const int* __restrict__ offsets,
    const int* __restrict__ list_tok, const float* __restrict__ list_gate,
    float* __restrict__ out)
{
    const int bid = blockIdx.x;
    const int e   = bid >> 9;
    const int r   = bid & 511;
    const int wg  = ((r & 7) << 6) + (r >> 3);
    const int n_t = wg >> 6;
    const int m_t = wg & 63;

    const int cnt = counts[e];
    const int m0  = m_t * 128;
    if (m0 >= cnt) return;
    const int base = offsets[e];
    const int n0   = n_t * 128;
    const u16* __restrict__ Be = W2t + (size_t)e * (D_MODEL * HID);

    __shared__ __align__(16) u16 SA[3 * 4096];
    __shared__ __align__(16) u16 SB[3 * 4096];
    __shared__ int   s_tok[128];
    __shared__ float s_gate[128];

    const int tid = threadIdx.x;
    if (tid < 128) {
        const int sl = base + min(m0 + tid, cnt - 1);
        s_tok[tid]  = list_tok[sl];
        s_gate[tid] = list_gate[sl];
    }
    __syncthreads();

    int ar0, ak0, ar1, ak1;
    chunk_map(tid, ar0, ak0);
    chunk_map(tid + 256, ar1, ak1);
    const u16* Asrc0 = Hb + (size_t)(base + min(m0 + ar0, cnt - 1)) * HID + ak0;
    const u16* Asrc1 = Hb + (size_t)(base + min(m0 + ar1, cnt - 1)) * HID + ak1;
    const u16* Bsrc0 = Be + (size_t)(n0 + ar0) * HID + ak0;
    const u16* Bsrc1 = Be + (size_t)(n0 + ar1) * HID + ak1;

    const int lane = tid & 63, l31 = lane & 31, l5 = lane >> 5;
    const int w = tid >> 6, wm = w >> 1, wn = w & 1;

    int offA[2][2], offB[2][2];
    #pragma unroll
    for (int f = 0; f < 2; ++f)
        #pragma unroll
        for (int ks = 0; ks < 2; ++ks) {
            offA[f][ks] = lds_off(wm * 64 + f * 32 + l31, ks * 2 + l5);
            offB[f][ks] = lds_off(wn * 64 + f * 32 + l31, ks * 2 + l5);
        }

    float bias2[2];
    #pragma unroll
    for (int f = 0; f < 2; ++f)
        bias2[f] = b2[(size_t)e * D_MODEL + n0 + wn * 64 + f * 32 + l31];

    f32x16 acc[2][2] = {};

    auto STAGE = [&](int s, int t) {
        const int kt = t * 32;
        char* Ab = (char*)SA + s * 8192;
        char* Bb = (char*)SB + s * 8192;
        glds16(Asrc0 + kt, Ab + tid * 16);
        glds16(Asrc1 + kt, Ab + (tid + 256) * 16);
        glds16(Bsrc0 + kt, Bb + tid * 16);
        glds16(Bsrc1 + kt, Bb + (tid + 256) * 16);
    };
    auto COMPUTE = [&](int s) {
        const char* Ab = (const char*)SA + s * 8192;
        const char* Bb = (const char*)SB + s * 8192;
        #pragma unroll
        for (int ks = 0; ks < 2; ++ks) {
            const bf16x8 a0 = *(const bf16x8*)(Ab + offA[0][ks]);
            const bf16x8 a1 = *(const bf16x8*)(Ab + offA[1][ks]);
            const bf16x8 b0 = *(const bf16x8*)(Bb + offB[0][ks]);
            const bf16x8 b1v = *(const bf16x8*)(Bb + offB[1][ks]);
            acc[0][0] = __builtin_amdgcn_mfma_f32_32x32x16_bf16(a0, b0,  acc[0][0], 0, 0, 0);
            acc[0][1] = __builtin_amdgcn_mfma_f32_32x32x16_bf16(a0, b1v, acc[0][1], 0, 0, 0);
            acc[1][0] = __builtin_amdgcn_mfma_f32_32x32x16_bf16(a1, b0,  acc[1][0], 0, 0, 0);
            acc[1][1] = __builtin_amdgcn_mfma_f32_32x32x16_bf16(a1, b1v, acc[1][1], 0, 0, 0);
        }
    };

    const int NT = HID / 32;                    // 128
    STAGE(0, 0);
    STAGE(1, 1);
    int sc = 0;
    for (int t = 0; t < NT; ++t) {
        if (t == NT - 1) { asm volatile("s_waitcnt vmcnt(0)" ::: "memory"); }
        else             { asm volatile("s_waitcnt vmcnt(4)" ::: "memory"); }
        __builtin_amdgcn_s_barrier();
        __builtin_amdgcn_sched_barrier(0);
        if (t + 2 < NT) { int ss = sc + 2; if (ss >= 3) ss -= 3; STAGE(ss, t + 2); }
        __builtin_amdgcn_sched_barrier(0);
        COMPUTE(sc);
        if (++sc == 3) sc = 0;
    }

    #pragma unroll
    for (int fi = 0; fi < 2; ++fi)
        #pragma unroll
        for (int fj = 0; fj < 2; ++fj)
            #pragma unroll
            for (int reg = 0; reg < 16; ++reg) {
                const int m = m0 + wm * 64 + fi * 32 + (reg & 3) + 8 * (reg >> 2) + 4 * l5;
                if (m < cnt) {
                    const int   mm = m - m0;
                    const int   tk = s_tok[mm];
                    const float gt = s_gate[mm];
                    unsafeAtomicAdd(out + (size_t)tk * D_MODEL + n0 + wn * 64 + fj * 32 + l31,
                                    gt * (acc[fi][fj][reg] + bias2[fj]));
                }
            }
}

// ---------------------------------------------------------------------------
extern "C" void kernel_launch(void* const* d_in, const int* in_sizes, int n_in,
                              void* d_out, int out_size, void* d_ws, size_t ws_size,
                              hipStream_t stream)
{
    const float* x     = (const float*)d_in[0];
    const float* noise = (const float*)d_in[1];
    const float* Wr    = (const float*)d_in[2];
    const float* br    = (const float*)d_in[3];
    const float* Wn    = (const float*)d_in[4];
    const float* bn    = (const float*)d_in[5];
    const float* W1    = (const float*)d_in[6];
    const float* b1    = (const float*)d_in[7];
    const float* W2    = (const float*)d_in[8];
    const float* b2    = (const float*)d_in[9];
    float* out = (float*)d_out;

    char* ws = (char*)d_ws;
    int*   counts    = (int*)(ws + WS_COUNTS);
    int*   cursor    = (int*)(ws + WS_CURSOR);
    int*   offsets   = (int*)(ws + WS_OFFSETS);
    int*   tok_e     = (int*)(ws + WS_TOKE);
    float* tok_g     = (float*)(ws + WS_TOKG);
    int*   list_tok  = (int*)(ws + WS_LTOK);
    float* list_gate = (float*)(ws + WS_LGATE);
    u16*   xb        = (u16*)(ws + WS_XB);
    u16*   Wb        = (u16*)(ws + WS_WB);
    u16*   Hb        = (u16*)(ws + WS_H);

    hipMemsetAsync(ws, 0, 128, stream);
    hipMemsetAsync(d_out, 0, (size_t)out_size * sizeof(float), stream);

    k_cvtT<<<dim3(HID / 32, D_MODEL / 64, N_EXP), 256, 0, stream>>>(W1, Wb, D_MODEL, HID);
    k_router<<<T_TOK, 256, 0, stream>>>(x, noise, Wr, br, Wn, bn, counts, tok_e, tok_g, xb);
    k_prefix<<<1, 64, 0, stream>>>(counts, offsets);
    k_scatter<<<NPAIR / 256, 256, 0, stream>>>(tok_e, tok_g, offsets, cursor,
                                               list_tok, list_gate);

    k_ffn1<<<N_EXP * 32 * 64, 256, 0, stream>>>(xb, Wb, b1, counts, offsets,
                                                list_tok, Hb);

    k_cvtT<<<dim3(D_MODEL / 32, HID / 64, N_EXP), 256, 0, stream>>>(W2, Wb, HID, D_MODEL);
    k_ffn2<<<N_EXP * 8 * 64, 256, 0, stream>>>(Hb, Wb, b2, counts, offsets,
                                               list_tok, list_gate, out);
}

// Round 6
// 453.876 us; speedup vs baseline: 1.1297x; 1.0469x over previous
//
#include <hip/hip_runtime.h>
#include <hip/hip_bf16.h>
#include <cstdint>
#include <cstddef>

#define D_MODEL 1024
#define N_EXP   8
#define HID     4096
#define T_TOK   4096          // B*S
#define NPAIR   (T_TOK * 2)   // top-2
#define WSLOTS  72            // max m-tiles total: 8192/128 + 7 = 71

// ---------------- workspace layout (bytes) ----------------
#define WS_COUNTS   0
#define WS_CURSOR   32
#define WS_OFFSETS  64
#define WS_TOKE     128                       // tok_e[T][2] int
#define WS_TOKG     32896                     // tok_g[T][2] float
#define WS_LTOK     65664                     // list_tok[NPAIR] int
#define WS_LGATE    98432                     // list_gate[NPAIR] float
#define WS_XB       131328                    // xb[T][1024] bf16        (8 MB)
#define WS_WB       (WS_XB + 8388608)         // Wt shared buf bf16      (64 MB)
#define WS_H        (WS_WB + 67108864)        // H[NPAIR][4096] bf16     (64 MB)

typedef __attribute__((ext_vector_type(8))) short bf16x8;
typedef __attribute__((ext_vector_type(4))) float f32x4;
typedef __attribute__((ext_vector_type(8))) unsigned short u16x8;
typedef unsigned short u16;

__device__ __forceinline__ u16 f2bf(float f) {
    unsigned u = __float_as_uint(f);
    u += 0x7FFFu + ((u >> 16) & 1u);          // RNE
    return (u16)(u >> 16);
}

__device__ __forceinline__ void glds16(const void* g, void* l) {
    __builtin_amdgcn_global_load_lds(
        (const __attribute__((address_space(1))) void*)g,
        (__attribute__((address_space(3))) void*)l, 16, 0, 0);
}

// Swizzled-stage chunk map (validated r3: conflicts 0, bit-exact output).
// LDS tile: 128 rows x 32 bf16, 2 rows per 128B line (8 x 16B chunks), chunk
// slot XOR-swizzled by (line&7). Read side uses matching XOR.
__device__ __forceinline__ void chunk_map(int c, int& row, int& kc) {
    const int line = c >> 3, c8 = c & 7, u = c8 ^ (line & 7);
    row = line * 2 + (u >> 2);
    kc  = (u & 3) * 8;                        // ushort offset in 32-wide K window
}

// compact worklist: slot w -> (expert, m_tile). uniform per block.
__device__ __forceinline__ bool work_map(const int* counts, int w,
                                         int& e, int& m_t) {
    int tot = 0; e = -1; m_t = 0;
    #pragma unroll
    for (int i = 0; i < N_EXP; ++i) {
        const int tl = (counts[i] + 127) >> 7;
        if (e < 0 && w < tot + tl) { e = i; m_t = w - tot; }
        tot += tl;
    }
    return e >= 0;
}

// ---------------------------------------------------------------------------
// Router (validated) + fused x -> bf16 emission (validated r4)
// ---------------------------------------------------------------------------
__global__ __launch_bounds__(256) void k_router(
    const float* __restrict__ x, const float* __restrict__ noise,
    const float* __restrict__ Wr, const float* __restrict__ br,
    const float* __restrict__ Wn, const float* __restrict__ bn,
    int* __restrict__ counts, int* __restrict__ tok_e, float* __restrict__ tok_g,
    u16* __restrict__ xb)
{
    const int t   = blockIdx.x;
    const int tid = threadIdx.x;
    const int e   = tid & 7;
    const int g   = tid >> 3;
    const float* xr = x + (size_t)t * D_MODEL;

    {
        const float4 v4 = *(const float4*)(xr + tid * 4);
        ushort4 o;
        o.x = f2bf(v4.x); o.y = f2bf(v4.y); o.z = f2bf(v4.z); o.w = f2bf(v4.w);
        *(ushort4*)(xb + (size_t)t * D_MODEL + tid * 4) = o;
    }

    float ar = 0.f, an = 0.f;
    const int ibase = g * 32;
    #pragma unroll 8
    for (int j = 0; j < 32; ++j) {
        const int i = ibase + j;
        const float xv = xr[i];
        ar = fmaf(xv, Wr[i * 8 + e], ar);
        an = fmaf(xv, Wn[i * 8 + e], an);
    }

    __shared__ float sR[256], sN[256];
    sR[tid] = ar; sN[tid] = an;
    __syncthreads();
    for (int off = 128; off >= 8; off >>= 1) {
        if (tid < off) { sR[tid] += sR[tid + off]; sN[tid] += sN[tid + off]; }
        __syncthreads();
    }

    __shared__ float lg[8];
    if (tid < 8) {
        const float z  = sN[tid] + bn[tid];
        const float sp = fmaxf(z, 0.f) + log1pf(expf(-fabsf(z)));
        lg[tid] = sR[tid] + br[tid] + sp * noise[t * 8 + tid];
    }
    __syncthreads();

    if (tid == 0) {
        float v0 = -INFINITY, v1 = -INFINITY;
        int   i0 = 0,         i1 = 0;
        #pragma unroll
        for (int ee = 0; ee < 8; ++ee) {
            const float v = lg[ee];
            if (v > v0)      { v1 = v0; i1 = i0; v0 = v; i0 = ee; }
            else if (v > v1) { v1 = v;  i1 = ee; }
        }
        const float ew  = expf(v1 - v0);
        const float inv = 1.f / (1.f + ew);
        tok_e[t * 2 + 0] = i0;
        tok_e[t * 2 + 1] = i1;
        tok_g[t * 2 + 0] = inv;
        tok_g[t * 2 + 1] = ew * inv;
        atomicAdd(&counts[i0], 1);
        atomicAdd(&counts[i1], 1);
    }
}

__global__ void k_prefix(const int* __restrict__ counts, int* __restrict__ offsets)
{
    if (threadIdx.x == 0 && blockIdx.x == 0) {
        int acc = 0;
        #pragma unroll
        for (int e = 0; e < N_EXP; ++e) { offsets[e] = acc; acc += counts[e]; }
    }
}

__global__ __launch_bounds__(256) void k_scatter(
    const int* __restrict__ tok_e, const float* __restrict__ tok_g,
    const int* __restrict__ offsets, int* __restrict__ cursor,
    int* __restrict__ list_tok, float* __restrict__ list_gate)
{
    const int gid = blockIdx.x * 256 + threadIdx.x;
    if (gid >= NPAIR) return;
    const int e = tok_e[gid];
    const int p = atomicAdd(&cursor[e], 1);
    const int slot = offsets[e] + p;
    list_tok[slot]  = gid >> 1;
    list_gate[slot] = tok_g[gid];
}

// ---------------------------------------------------------------------------
// Per-expert transpose+convert: f32 [E][R][C] -> bf16 [E][C][R]  (r5 version)
// ---------------------------------------------------------------------------
__global__ __launch_bounds__(256) void k_cvtT(
    const float* __restrict__ in, u16* __restrict__ outp, int R, int C)
{
    const size_t esz = (size_t)R * C;
    const float* ine = in + (size_t)blockIdx.z * esz;
    u16* oute = outp + (size_t)blockIdx.z * esz;
    const int c0 = blockIdx.x * 32, r0 = blockIdx.y * 64;

    __shared__ u16 s[64 * 33];
    const int tid = threadIdx.x;
    const int lr = tid >> 3, lc = (tid & 7) * 4;
    #pragma unroll
    for (int p = 0; p < 2; ++p) {
        const int row = lr + p * 32;
        const float4 v = *(const float4*)(ine + (size_t)(r0 + row) * C + c0 + lc);
        s[row * 33 + lc + 0] = f2bf(v.x);
        s[row * 33 + lc + 1] = f2bf(v.y);
        s[row * 33 + lc + 2] = f2bf(v.z);
        s[row * 33 + lc + 3] = f2bf(v.w);
    }
    __syncthreads();
    const int oc = tid >> 3, rr = (tid & 7) * 8;
    u16x8 o;
    #pragma unroll
    for (int i = 0; i < 8; ++i) o[i] = s[(rr + i) * 33 + oc];
    *(u16x8*)(oute + (size_t)(c0 + oc) * R + r0 + rr) = o;
}

// ---------------------------------------------------------------------------
// Grouped MFMA GEMM1: H = relu(Xg @ W1t^T + b1).
// r3-validated 128x128 / 16x16x32 core; DOUBLE-buffered (33 KB LDS ->
// 4 blocks/CU) with counted vmcnt(4); compact worklist grid (no dead blocks).
// grid = 32 n * WSLOTS; n_t&7 = XCD (B panels XCD-exclusive).
// ---------------------------------------------------------------------------
__global__ __launch_bounds__(256, 4) void k_ffn1(
    const u16* __restrict__ xb,     // [T][1024]
    const u16* __restrict__ W1t,    // [E][4096][1024]
    const float* __restrict__ b1,
    const int* __restrict__ counts, const int* __restrict__ offsets,
    const int* __restrict__ list_tok,
    u16* __restrict__ H)            // [NPAIR][4096]
{
    const int bid = blockIdx.x;
    const int n_t = (bid & 7) | (((bid >> 3) & 3) << 3);   // 0..31, n_t&7 = XCD
    const int wsl = bid >> 5;

    int e, m_t;
    if (!work_map(counts, wsl, e, m_t)) return;
    const int cnt  = counts[e];
    const int base = offsets[e];
    const int m0   = m_t * 128;
    const int n0   = n_t * 128;
    const u16* __restrict__ Be = W1t + (size_t)e * (HID * D_MODEL);

    __shared__ __align__(16) u16 SA[2 * 4096];  // 2 x (128 x 32) bf16 = 16 KB
    __shared__ __align__(16) u16 SB[2 * 4096];
    __shared__ int stok[128];

    const int tid = threadIdx.x;
    if (tid < 128) stok[tid] = list_tok[base + min(m0 + tid, cnt - 1)];
    __syncthreads();

    int ar0, ak0, ar1, ak1;
    chunk_map(tid, ar0, ak0);
    chunk_map(tid + 256, ar1, ak1);
    const u16* Asrc0 = xb + (size_t)stok[ar0] * D_MODEL + ak0;
    const u16* Asrc1 = xb + (size_t)stok[ar1] * D_MODEL + ak1;
    const u16* Bsrc0 = Be + (size_t)(n0 + ar0) * D_MODEL + ak0;
    const u16* Bsrc1 = Be + (size_t)(n0 + ar1) * D_MODEL + ak1;

    const int lane = tid & 63, lr = lane & 15, hk = lane >> 4;
    const int w = tid >> 6, wm = w >> 1, wn = w & 1;
    const int colb  = ((((lr & 1) << 2) + hk) ^ (lr >> 1)) << 4;
    const int baseA = ((wm * 32 + (lr >> 1)) << 7) + colb;
    const int baseB = ((wn * 32 + (lr >> 1)) << 7) + colb;

    float bias[4];
    #pragma unroll
    for (int j = 0; j < 4; ++j) bias[j] = b1[(size_t)e * HID + n0 + wn * 64 + j * 16 + lr];

    f32x4 acc[4][4] = {};

    auto STAGE = [&](int s, int t) {
        const int kt = t * 32;
        char* Ab = (char*)SA + s * 8192;
        char* Bb = (char*)SB + s * 8192;
        glds16(Asrc0 + kt, Ab + tid * 16);
        glds16(Asrc1 + kt, Ab + (tid + 256) * 16);
        glds16(Bsrc0 + kt, Bb + tid * 16);
        glds16(Bsrc1 + kt, Bb + (tid + 256) * 16);
    };
    auto COMPUTE = [&](int s) {
        const char* Ab = (const char*)SA + s * 8192;
        const char* Bb = (const char*)SB + s * 8192;
        bf16x8 a[4], b[4];
        #pragma unroll
        for (int i = 0; i < 4; ++i) a[i] = *(const bf16x8*)(Ab + baseA + i * 1024);
        #pragma unroll
        for (int j = 0; j < 4; ++j) b[j] = *(const bf16x8*)(Bb + baseB + j * 1024);
        #pragma unroll
        for (int i = 0; i < 4; ++i)
            #pragma unroll
            for (int j = 0; j < 4; ++j)
                acc[i][j] = __builtin_amdgcn_mfma_f32_16x16x32_bf16(a[i], b[j], acc[i][j], 0, 0, 0);
    };

    const int NT = D_MODEL / 32;                // 32
    STAGE(0, 0);
    STAGE(1, 1);
    for (int t = 0; t < NT; ++t) {
        if (t < NT - 1) { asm volatile("s_waitcnt vmcnt(4)" ::: "memory"); }
        else            { asm volatile("s_waitcnt vmcnt(0)" ::: "memory"); }
        __builtin_amdgcn_s_barrier();
        __builtin_amdgcn_sched_barrier(0);
        COMPUTE(t & 1);
        __builtin_amdgcn_sched_barrier(0);
        __builtin_amdgcn_s_barrier();           // all reads of buf (t&1) done
        if (t + 2 < NT) STAGE(t & 1, t + 2);    // overwrite it for t+2
    }

    #pragma unroll
    for (int i = 0; i < 4; ++i) {
        #pragma unroll
        for (int g = 0; g < 4; ++g) {
            const int m = m0 + wm * 64 + i * 16 + hk * 4 + g;
            if (m < cnt) {
                u16* dst = H + (size_t)(base + m) * HID + n0 + wn * 64 + lr;
                #pragma unroll
                for (int j = 0; j < 4; ++j)
                    dst[j * 16] = f2bf(fmaxf(acc[i][j][g] + bias[j], 0.f));
            }
        }
    }
}

// ---------------------------------------------------------------------------
// Grouped MFMA GEMM2: out += gate*(H @ W2t^T + b2). K=4096. Same pipeline.
// grid = 8 n * WSLOTS; n_t = XCD-exclusive (W2t panel L2-resident).
// ---------------------------------------------------------------------------
__global__ __launch_bounds__(256, 4) void k_ffn2(
    const u16* __restrict__ Hb,     // [NPAIR][4096]
    const u16* __restrict__ W2t,    // [E][1024][4096]
    const float* __restrict__ b2,
    const int* __restrict__ counts, const int* __restrict__ offsets,
    const int* __restrict__ list_tok, const float* __restrict__ list_gate,
    float* __restrict__ out)
{
    const int bid = blockIdx.x;
    const int n_t = bid & 7;
    const int wsl = bid >> 3;

    int e, m_t;
    if (!work_map(counts, wsl, e, m_t)) return;
    const int cnt  = counts[e];
    const int base = offsets[e];
    const int m0   = m_t * 128;
    const int n0   = n_t * 128;
    const u16* __restrict__ Be = W2t + (size_t)e * (D_MODEL * HID);

    __shared__ __align__(16) u16 SA[2 * 4096];
    __shared__ __align__(16) u16 SB[2 * 4096];
    __shared__ int   s_tok[128];
    __shared__ float s_gate[128];

    const int tid = threadIdx.x;
    if (tid < 128) {
        const int sl = base + min(m0 + tid, cnt - 1);
        s_tok[tid]  = list_tok[sl];
        s_gate[tid] = list_gate[sl];
    }
    __syncthreads();

    int ar0, ak0, ar1, ak1;
    chunk_map(tid, ar0, ak0);
    chunk_map(tid + 256, ar1, ak1);
    const u16* Asrc0 = Hb + (size_t)(base + min(m0 + ar0, cnt - 1)) * HID + ak0;
    const u16* Asrc1 = Hb + (size_t)(base + min(m0 + ar1, cnt - 1)) * HID + ak1;
    const u16* Bsrc0 = Be + (size_t)(n0 + ar0) * HID + ak0;
    const u16* Bsrc1 = Be + (size_t)(n0 + ar1) * HID + ak1;

    const int lane = tid & 63, lr = lane & 15, hk = lane >> 4;
    const int w = tid >> 6, wm = w >> 1, wn = w & 1;
    const int colb  = ((((lr & 1) << 2) + hk) ^ (lr >> 1)) << 4;
    const int baseA = ((wm * 32 + (lr >> 1)) << 7) + colb;
    const int baseB = ((wn * 32 + (lr >> 1)) << 7) + colb;

    float bias[4];
    #pragma unroll
    for (int j = 0; j < 4; ++j) bias[j] = b2[(size_t)e * D_MODEL + n0 + wn * 64 + j * 16 + lr];

    f32x4 acc[4][4] = {};

    auto STAGE = [&](int s, int t) {
        const int kt = t * 32;
        char* Ab = (char*)SA + s * 8192;
        char* Bb = (char*)SB + s * 8192;
        glds16(Asrc0 + kt, Ab + tid * 16);
        glds16(Asrc1 + kt, Ab + (tid + 256) * 16);
        glds16(Bsrc0 + kt, Bb + tid * 16);
        glds16(Bsrc1 + kt, Bb + (tid + 256) * 16);
    };
    auto COMPUTE = [&](int s) {
        const char* Ab = (const char*)SA + s * 8192;
        const char* Bb = (const char*)SB + s * 8192;
        bf16x8 a[4], b[4];
        #pragma unroll
        for (int i = 0; i < 4; ++i) a[i] = *(const bf16x8*)(Ab + baseA + i * 1024);
        #pragma unroll
        for (int j = 0; j < 4; ++j) b[j] = *(const bf16x8*)(Bb + baseB + j * 1024);
        #pragma unroll
        for (int i = 0; i < 4; ++i)
            #pragma unroll
            for (int j = 0; j < 4; ++j)
                acc[i][j] = __builtin_amdgcn_mfma_f32_16x16x32_bf16(a[i], b[j], acc[i][j], 0, 0, 0);
    };

    const int NT = HID / 32;                    // 128
    STAGE(0, 0);
    STAGE(1, 1);
    for (int t = 0; t < NT; ++t) {
        if (t < NT - 1) { asm volatile("s_waitcnt vmcnt(4)" ::: "memory"); }
        else            { asm volatile("s_waitcnt vmcnt(0)" ::: "memory"); }
        __builtin_amdgcn_s_barrier();
        __builtin_amdgcn_sched_barrier(0);
        COMPUTE(t & 1);
        __builtin_amdgcn_sched_barrier(0);
        __builtin_amdgcn_s_barrier();
        if (t + 2 < NT) STAGE(t & 1, t + 2);
    }

    #pragma unroll
    for (int i = 0; i < 4; ++i) {
        #pragma unroll
        for (int g = 0; g < 4; ++g) {
            const int m = m0 + wm * 64 + i * 16 + hk * 4 + g;
            if (m < cnt) {
                const int   mm = m - m0;
                const int   tk = s_tok[mm];
                const float gt = s_gate[mm];
                float* dst = out + (size_t)tk * D_MODEL + n0 + wn * 64 + lr;
                #pragma unroll
                for (int j = 0; j < 4; ++j)
                    unsafeAtomicAdd(dst + j * 16, gt * (acc[i][j][g] + bias[j]));
            }
        }
    }
}

// ---------------------------------------------------------------------------
extern "C" void kernel_launch(void* const* d_in, const int* in_sizes, int n_in,
                              void* d_out, int out_size, void* d_ws, size_t ws_size,
                              hipStream_t stream)
{
    const float* x     = (const float*)d_in[0];
    const float* noise = (const float*)d_in[1];
    const float* Wr    = (const float*)d_in[2];
    const float* br    = (const float*)d_in[3];
    const float* Wn    = (const float*)d_in[4];
    const float* bn    = (const float*)d_in[5];
    const float* W1    = (const float*)d_in[6];
    const float* b1    = (const float*)d_in[7];
    const float* W2    = (const float*)d_in[8];
    const float* b2    = (const float*)d_in[9];
    float* out = (float*)d_out;

    char* ws = (char*)d_ws;
    int*   counts    = (int*)(ws + WS_COUNTS);
    int*   cursor    = (int*)(ws + WS_CURSOR);
    int*   offsets   = (int*)(ws + WS_OFFSETS);
    int*   tok_e     = (int*)(ws + WS_TOKE);
    float* tok_g     = (float*)(ws + WS_TOKG);
    int*   list_tok  = (int*)(ws + WS_LTOK);
    float* list_gate = (float*)(ws + WS_LGATE);
    u16*   xb        = (u16*)(ws + WS_XB);
    u16*   Wb        = (u16*)(ws + WS_WB);
    u16*   Hb        = (u16*)(ws + WS_H);

    hipMemsetAsync(ws, 0, 128, stream);
    hipMemsetAsync(d_out, 0, (size_t)out_size * sizeof(float), stream);

    k_cvtT<<<dim3(HID / 32, D_MODEL / 64, N_EXP), 256, 0, stream>>>(W1, Wb, D_MODEL, HID);
    k_router<<<T_TOK, 256, 0, stream>>>(x, noise, Wr, br, Wn, bn, counts, tok_e, tok_g, xb);
    k_prefix<<<1, 64, 0, stream>>>(counts, offsets);
    k_scatter<<<NPAIR / 256, 256, 0, stream>>>(tok_e, tok_g, offsets, cursor,
                                               list_tok, list_gate);

    k_ffn1<<<32 * WSLOTS, 256, 0, stream>>>(xb, Wb, b1, counts, offsets,
                                            list_tok, Hb);

    k_cvtT<<<dim3(D_MODEL / 32, HID / 64, N_EXP), 256, 0, stream>>>(W2, Wb, HID, D_MODEL);
    k_ffn2<<<8 * WSLOTS, 256, 0, stream>>>(Hb, Wb, b2, counts, offsets,
                                           list_tok, list_gate, out);
}